// Round 4
// baseline (5788.204 us; speedup 1.0000x reference)
//
#include <hip/hip_runtime.h>
#include <hip/hip_bf16.h>

typedef __attribute__((ext_vector_type(8))) short short8;
typedef __attribute__((ext_vector_type(4))) float f32x4;
typedef unsigned long long u64;
typedef unsigned int u32;

#define SQLEN 256
#define BATCH 128
#define HID   1024
#define G4    4096
#define NCLS  1000

static __device__ __forceinline__ float sigm(float x){ return 1.0f/(1.0f+__expf(-x)); }
static __device__ __forceinline__ float tanhx(float x){ return 2.0f/(1.0f+__expf(-2.0f*x)) - 1.0f; }
static __device__ __forceinline__ short bf16b(float x){
  __hip_bfloat16 h = __float2bfloat16(x);
  return __builtin_bit_cast(short, h);
}
static __device__ __forceinline__ float bf2f(short s){
  return __bfloat162float(__builtin_bit_cast(__hip_bfloat16, s));
}

// ---- prep: cast x [B][S][I] fp32 -> xbf [(s*128+b)][I] bf16 (permuted) ----
__global__ void cast_x_kernel(const float* __restrict__ x, short* __restrict__ xbf){
  int r = blockIdx.x;            // r = s*128 + b
  int s = r >> 7, b = r & 127;
  const float* src = x + ((size_t)b*SQLEN + s)*HID;
  short* dst = xbf + (size_t)r*HID;
  int k = threadIdx.x*4;
  float4 v = *(const float4*)(src + k);
  short4 o; o.x=bf16b(v.x); o.y=bf16b(v.y); o.z=bf16b(v.z); o.w=bf16b(v.w);
  *(short4*)(dst + k) = o;
}

__global__ void cast_w_kernel(const float* __restrict__ src, short* __restrict__ dst){
  int i = (blockIdx.x*256 + threadIdx.x)*4;
  float4 v = *(const float4*)(src + i);
  short4 o; o.x=bf16b(v.x); o.y=bf16b(v.y); o.z=bf16b(v.z); o.w=bf16b(v.w);
  *(short4*)(dst + i) = o;
}

__global__ void bias_kernel(const float* __restrict__ a, const float* __restrict__ b,
                            float* __restrict__ o){
  int i = blockIdx.x*256 + threadIdx.x;
  o[i] = a[i] + b[i];
}

// ---- phase 1: xw GEMM. Output in gate-blocked layout:
//   xw2[((s*64 + jg)*128 + b)*64 + g*16 + jj]
__global__ __launch_bounds__(256,2) void gemm_xw_kernel(
    const short* __restrict__ A, const short* __restrict__ B,
    const float* __restrict__ bias, short* __restrict__ C)
{
  __shared__ __align__(16) short As[4096];   // [128][32]
  __shared__ __align__(16) short Bs[4096];
  const int tid = threadIdx.x;
  const int bm = blockIdx.x >> 5;     // 0..255  (= s index)
  const int bn = blockIdx.x & 31;     // 0..31
  const size_t r0 = (size_t)bm*128, n0 = (size_t)bn*128;
  const int lane = tid & 63, wave = tid >> 6;
  const int wm = (wave>>1)*64, wn = (wave&1)*64;
  const int l15 = lane & 15, quad = lane >> 4;

  f32x4 acc[4][4];
  #pragma unroll
  for (int m=0;m<4;++m)
    #pragma unroll
    for (int n=0;n<4;++n) acc[m][n] = (f32x4)0.0f;

  for (int kk = 0; kk < 32; ++kk){
    const int k0 = kk*32;
    short8 av[2], bv[2];
    #pragma unroll
    for (int rep=0; rep<2; ++rep){
      int c = rep*256 + tid;
      int row = c >> 2, ko = (c & 3)*8;
      av[rep] = *(const short8*)(A + (r0+row)*HID + k0 + ko);
      bv[rep] = *(const short8*)(B + (n0+row)*HID + k0 + ko);
    }
    __syncthreads();
    #pragma unroll
    for (int rep=0; rep<2; ++rep){
      int c = rep*256 + tid;
      *(short8*)(As + c*8) = av[rep];
      *(short8*)(Bs + c*8) = bv[rep];
    }
    __syncthreads();
    short8 af[4], bf[4];
    #pragma unroll
    for (int m=0;m<4;++m) af[m] = *(const short8*)(As + (wm + m*16 + l15)*32 + quad*8);
    #pragma unroll
    for (int n=0;n<4;++n) bf[n] = *(const short8*)(Bs + (wn + n*16 + l15)*32 + quad*8);
    #pragma unroll
    for (int m=0;m<4;++m)
      #pragma unroll
      for (int n=0;n<4;++n)
        acc[m][n] = __builtin_amdgcn_mfma_f32_16x16x32_bf16(af[m], bf[n], acc[m][n], 0,0,0);
  }
  __syncthreads();
  #pragma unroll
  for (int n=0;n<4;++n){
    int nn = (int)n0 + wn + n*16 + l15;           // 0..4095
    float bs = bias[nn];
    int g = nn >> 10, jcol = nn & 1023;
    int jgi = jcol >> 4, jji = jcol & 15;
    #pragma unroll
    for (int m=0;m<4;++m){
      #pragma unroll
      for (int rg=0; rg<4; ++rg){
        int rowin = wm + m*16 + quad*4 + rg;      // 0..127 (= batch b)
        size_t dst = (((size_t)bm*64 + jgi)*128 + rowin)*64 + g*16 + jji;
        C[dst] = bf16b(acc[m][n][rg] + bs);
      }
    }
  }
}

// ---- phase 2: persistent LSTM recurrence ----
// 256 blocks x 512 threads. 4 b-groups (32 rows) x 64 j-groups (16 hid).
// Whh slice in LDS (132 KB, padded rows). h read via normal CACHED coalesced
// loads + one agent acquire fence per step; h written via 8B sc1 atomic
// stores (write-through to MALL). xw prefetched one step ahead in registers.
__global__ __launch_bounds__(512,2) void lstm_kernel(
    const short* __restrict__ whh, const short* __restrict__ xw,
    short* __restrict__ h0, short* __restrict__ h1, u32* __restrict__ flags)
{
  __shared__ __align__(16) short whh_s[4*16*1032];   // 132096 B, row pad +8
  __shared__ f32x4 part[8][2][64];                   // 16384 B

  const int tid  = threadIdx.x;
  const int lane = tid & 63;
  const int wave = tid >> 6;         // K-slice 0..7 (128 each)
  const int l15  = lane & 15;
  const int quad = lane >> 4;
  const int bg = blockIdx.x >> 6;    // 0..3
  const int jg = blockIdx.x & 63;    // 0..63
  const int b0 = bg*32;
  const int j0 = jg*16;
  const int ks0 = wave*128;

  // preload Whh slice -> LDS: row (g*16+j) <- whh[(g*1024 + j0 + j)][:]
  for (int it = tid; it < 8192; it += 512){
    int row = it >> 7;               // 0..63
    int ck  = (it & 127) * 8;        // k offset (shorts)
    int g = row >> 4, j = row & 15;
    *(short8*)(whh_s + row*1032 + ck) =
        *(const short8*)(whh + (size_t)(g*1024 + j0 + j)*HID + ck);
  }

  u32* myflags = flags + bg*64;

  // elementwise mapping: cell = tid (512 cells: bl 0..31 x jj 0..15)
  const int bl = tid >> 4;
  const int jj = tid & 15;
  const int mt_e = bl >> 4, re = bl & 15;
  const int ln = (re>>2)*16 + jj, rg = re & 3;
  float cc = 0.0f;                   // cell state in register

  // prefetch xw for t=0
  short xwc[4];
  {
    const short* xb = xw + (((size_t)0*64 + jg)*128 + b0 + bl)*64 + jj;
    #pragma unroll
    for (int g=0; g<4; ++g) xwc[g] = xb[g*16];
  }
  __syncthreads();   // whh_s ready

  for (int t = 0; t < SQLEN; ++t){
    const short* hin  = (t & 1) ? h1 : h0;
    short*       hout = (t & 1) ? h0 : h1;

    // acquire: invalidate L1/L2 so cached h loads see MALL-fresh data.
    // Executed by every wave (per-wave ordering), once per step.
    if (t) __builtin_amdgcn_fence(__ATOMIC_ACQUIRE, "agent");

    // h fragments: normal cached coalesced 16B loads (16 lines/instr/wave)
    short8 Af[2][4];
    #pragma unroll
    for (int kit=0; kit<4; ++kit){
      #pragma unroll
      for (int mt=0; mt<2; ++mt)
        Af[mt][kit] = *(const short8*)(hin + (size_t)(b0 + mt*16 + l15)*HID
                                       + ks0 + kit*32 + quad*8);
    }

    // prefetch next step's xw into registers (survives next fence's inv)
    short xwn[4];
    if (t < SQLEN-1){
      const short* xb = xw + (((size_t)(t+1)*64 + jg)*128 + b0 + bl)*64 + jj;
      #pragma unroll
      for (int g=0; g<4; ++g) xwn[g] = xb[g*16];
    }

    f32x4 acc[2][4];
    #pragma unroll
    for (int mt=0; mt<2; ++mt)
      #pragma unroll
      for (int g=0; g<4; ++g) acc[mt][g] = (f32x4)0.0f;

    #pragma unroll
    for (int kit=0; kit<4; ++kit){
      #pragma unroll
      for (int g=0; g<4; ++g){
        short8 bfr = *(const short8*)(whh_s + (g*16 + l15)*1032 + ks0 + kit*32 + quad*8);
        acc[0][g] = __builtin_amdgcn_mfma_f32_16x16x32_bf16(Af[0][kit], bfr, acc[0][g],0,0,0);
        acc[1][g] = __builtin_amdgcn_mfma_f32_16x16x32_bf16(Af[1][kit], bfr, acc[1][g],0,0,0);
      }
    }

    // 4-stage cross-wave gate reduce (16 KB part)
    float gv[4];
    #pragma unroll
    for (int g=0; g<4; ++g){
      part[wave][0][lane] = acc[0][g];
      part[wave][1][lane] = acc[1][g];
      __syncthreads();
      float s = bf2f(xwc[g]);
      #pragma unroll
      for (int w=0; w<8; ++w)
        s += ((const float*)&part[w][mt_e][ln])[rg];
      gv[g] = s;
      __syncthreads();
    }

    float it = sigm(gv[0]), ft = sigm(gv[1]), ch = tanhx(gv[2]), ot = sigm(gv[3]);
    cc = cc*ft + it*ch;
    float hv = ot * tanhx(cc);

    // pack 4 adjacent cells -> one 8B sc1 atomic store (lane&3==0)
    float h1v = __shfl_down(hv, 1);
    float h2v = __shfl_down(hv, 2);
    float h3v = __shfl_down(hv, 3);
    if (!(lane & 3)){
      u64 hp =  (u64)(unsigned short)bf16b(hv)
             | ((u64)(unsigned short)bf16b(h1v) << 16)
             | ((u64)(unsigned short)bf16b(h2v) << 32)
             | ((u64)(unsigned short)bf16b(h3v) << 48);
      __hip_atomic_store((u64*)(hout + (size_t)(b0 + bl)*HID + j0 + jj), hp,
                         __ATOMIC_RELAXED, __HIP_MEMORY_SCOPE_AGENT);
    }
    xwc[0]=xwn[0]; xwc[1]=xwn[1]; xwc[2]=xwn[2]; xwc[3]=xwn[3];
    __syncthreads();   // h stores drained (vmcnt0 at barrier)

    if (t < SQLEN-1){
      if (tid == 0)
        __hip_atomic_store(myflags + jg, (u32)(t+1),
                           __ATOMIC_RELAXED, __HIP_MEMORY_SCOPE_AGENT);
      if (wave == 0){
        const u32 target = (u32)(t+1);
        while (!__all((int)(__hip_atomic_load(myflags + lane, __ATOMIC_RELAXED,
                                              __HIP_MEMORY_SCOPE_AGENT) >= target)))
          __builtin_amdgcn_s_sleep(1);
      }
      __syncthreads();
    }
  }
}

// ---- phase 3: out[b][c] = h[b]. Wfc[c] + bfc[c], fp32 ----
__global__ __launch_bounds__(256) void fc_kernel(const short* __restrict__ h,
    const float* __restrict__ wfc, const float* __restrict__ bfc, float* __restrict__ out)
{
  __shared__ float hs[4][1024];
  int tid = threadIdx.x;
  int b0 = blockIdx.x*4;
  for (int i = tid; i < 4096; i += 256){
    int bb = i >> 10, k = i & 1023;
    hs[bb][k] = bf2f(h[(size_t)(b0+bb)*HID + k]);
  }
  __syncthreads();
  for (int c = tid; c < NCLS; c += 256){
    const float* w = wfc + (size_t)c*HID;
    float a0=0.f,a1=0.f,a2=0.f,a3=0.f;
    for (int k=0; k<1024; k+=4){
      float4 wv = *(const float4*)(w + k);
      a0 += wv.x*hs[0][k] + wv.y*hs[0][k+1] + wv.z*hs[0][k+2] + wv.w*hs[0][k+3];
      a1 += wv.x*hs[1][k] + wv.y*hs[1][k+1] + wv.z*hs[1][k+2] + wv.w*hs[1][k+3];
      a2 += wv.x*hs[2][k] + wv.y*hs[2][k+1] + wv.z*hs[2][k+2] + wv.w*hs[2][k+3];
      a3 += wv.x*hs[3][k] + wv.y*hs[3][k+1] + wv.z*hs[3][k+2] + wv.w*hs[3][k+3];
    }
    float bb = bfc[c];
    out[(size_t)(b0+0)*NCLS + c] = a0 + bb;
    out[(size_t)(b0+1)*NCLS + c] = a1 + bb;
    out[(size_t)(b0+2)*NCLS + c] = a2 + bb;
    out[(size_t)(b0+3)*NCLS + c] = a3 + bb;
  }
}

extern "C" void kernel_launch(void* const* d_in, const int* in_sizes, int n_in,
                              void* d_out, int out_size, void* d_ws, size_t ws_size,
                              hipStream_t stream) {
  const float* x   = (const float*)d_in[0];
  const float* Wxh = (const float*)d_in[1];
  const float* bxh = (const float*)d_in[2];
  const float* Whh = (const float*)d_in[3];
  const float* bhh = (const float*)d_in[4];
  const float* Wfc = (const float*)d_in[5];
  const float* bfc = (const float*)d_in[6];
  float* out = (float*)d_out;

  char* ws = (char*)d_ws;
  short*    xbf   = (short*)(ws + 0);            // 64MB
  short*    wxhb  = (short*)(ws + 67108864);     // 8MB
  short*    whhb  = (short*)(ws + 75497472);     // 8MB
  float*    biasg = (float*)(ws + 83886080);     // 16KB
  short*    xw    = (short*)(ws + 83951616);     // 256MB (gate-blocked layout)
  short*    h0    = (short*)(ws + 352387072);    // 256KB
  short*    h1    = (short*)(ws + 352649216);    // 256KB
  u32*      flags = (u32*)(ws + 352911360);      // 4 groups x 64 words

  hipMemsetAsync(ws + 352387072, 0, 2*262144 + 4096, stream);

  cast_x_kernel<<<32768, 256, 0, stream>>>(x, xbf);
  cast_w_kernel<<<4096, 256, 0, stream>>>(Wxh, wxhb);
  cast_w_kernel<<<4096, 256, 0, stream>>>(Whh, whhb);
  bias_kernel  <<<16,   256, 0, stream>>>(bxh, bhh, biasg);
  gemm_xw_kernel<<<8192, 256, 0, stream>>>(xbf, wxhb, biasg, xw);
  lstm_kernel  <<<256,  512, 0, stream>>>(whhb, xw, h0, h1, flags);
  fc_kernel    <<<32,   256, 0, stream>>>(h0, Wfc, bfc, out);
}

// Round 5
// 2090.555 us; speedup vs baseline: 2.7687x; 2.7687x over previous
//
#include <hip/hip_runtime.h>
#include <hip/hip_bf16.h>

typedef __attribute__((ext_vector_type(8))) short short8;
typedef __attribute__((ext_vector_type(4))) float f32x4;
typedef unsigned long long u64;
typedef unsigned int u32;

#define SQLEN 256
#define BATCH 128
#define HID   1024
#define G4    4096
#define NCLS  1000

static __device__ __forceinline__ float sigm(float x){ return 1.0f/(1.0f+__expf(-x)); }
static __device__ __forceinline__ float tanhx(float x){ return 2.0f/(1.0f+__expf(-2.0f*x)) - 1.0f; }
static __device__ __forceinline__ short bf16b(float x){
  __hip_bfloat16 h = __float2bfloat16(x);
  return __builtin_bit_cast(short, h);
}
static __device__ __forceinline__ float bf2f(short s){
  return __bfloat162float(__builtin_bit_cast(__hip_bfloat16, s));
}

// ---- prep: cast x [B][S][I] fp32 -> xbf [(s*128+b)][I] bf16 (permuted) ----
__global__ void cast_x_kernel(const float* __restrict__ x, short* __restrict__ xbf){
  int r = blockIdx.x;            // r = s*128 + b
  int s = r >> 7, b = r & 127;
  const float* src = x + ((size_t)b*SQLEN + s)*HID;
  short* dst = xbf + (size_t)r*HID;
  int k = threadIdx.x*4;
  float4 v = *(const float4*)(src + k);
  short4 o; o.x=bf16b(v.x); o.y=bf16b(v.y); o.z=bf16b(v.z); o.w=bf16b(v.w);
  *(short4*)(dst + k) = o;
}

__global__ void cast_w_kernel(const float* __restrict__ src, short* __restrict__ dst){
  int i = (blockIdx.x*256 + threadIdx.x)*4;
  float4 v = *(const float4*)(src + i);
  short4 o; o.x=bf16b(v.x); o.y=bf16b(v.y); o.z=bf16b(v.z); o.w=bf16b(v.w);
  *(short4*)(dst + i) = o;
}

__global__ void bias_kernel(const float* __restrict__ a, const float* __restrict__ b,
                            float* __restrict__ o){
  int i = blockIdx.x*256 + threadIdx.x;
  o[i] = a[i] + b[i];
}

// ---- phase 1: xw GEMM (M=32768,N=4096,K=1024). global_load_lds staging.
// Output gate-blocked: xw[((s*64 + jg)*128 + b)*64 + g*16 + jj]
__global__ __launch_bounds__(256,3) void gemm_xw_kernel(
    const short* __restrict__ A, const short* __restrict__ B,
    const float* __restrict__ bias, short* __restrict__ C)
{
  __shared__ __align__(16) short As[4096];   // [128][32]
  __shared__ __align__(16) short Bs[4096];
  const int tid = threadIdx.x;
  const int bm = blockIdx.x >> 5;     // 0..255  (= s index)
  const int bn = blockIdx.x & 31;     // 0..31
  const size_t r0 = (size_t)bm*128, n0 = (size_t)bn*128;
  const int lane = tid & 63, wave = tid >> 6;
  const int wm = (wave>>1)*64, wn = (wave&1)*64;
  const int l15 = lane & 15, quad = lane >> 4;

  f32x4 acc[4][4];
  #pragma unroll
  for (int m=0;m<4;++m)
    #pragma unroll
    for (int n=0;n<4;++n) acc[m][n] = (f32x4)0.0f;

  const int c0 = wave*64 + lane;      // staging slot, rep 0
  const int c1 = c0 + 256;            // rep 1

  for (int kk = 0; kk < 32; ++kk){
    const int k0 = kk*32;
    __syncthreads();   // previous iter's LDS reads done
    // async DMA global -> LDS, 16B per lane, lane-contiguous dest
    __builtin_amdgcn_global_load_lds(
        (const void*)(A + (r0 + (c0>>2))*HID + k0 + (c0&3)*8),
        (void*)((char*)As + wave*1024), 16, 0, 0);
    __builtin_amdgcn_global_load_lds(
        (const void*)(A + (r0 + (c1>>2))*HID + k0 + (c1&3)*8),
        (void*)((char*)As + 4096 + wave*1024), 16, 0, 0);
    __builtin_amdgcn_global_load_lds(
        (const void*)(B + (n0 + (c0>>2))*HID + k0 + (c0&3)*8),
        (void*)((char*)Bs + wave*1024), 16, 0, 0);
    __builtin_amdgcn_global_load_lds(
        (const void*)(B + (n0 + (c1>>2))*HID + k0 + (c1&3)*8),
        (void*)((char*)Bs + 4096 + wave*1024), 16, 0, 0);
    __syncthreads();   // DMA landed (barrier drains vmcnt)
    short8 af[4], bf[4];
    #pragma unroll
    for (int m=0;m<4;++m) af[m] = *(const short8*)(As + (wm + m*16 + l15)*32 + quad*8);
    #pragma unroll
    for (int n=0;n<4;++n) bf[n] = *(const short8*)(Bs + (wn + n*16 + l15)*32 + quad*8);
    #pragma unroll
    for (int m=0;m<4;++m)
      #pragma unroll
      for (int n=0;n<4;++n)
        acc[m][n] = __builtin_amdgcn_mfma_f32_16x16x32_bf16(af[m], bf[n], acc[m][n], 0,0,0);
  }
  // epilogue: pack 4 adjacent bf16 -> 8B stores
  #pragma unroll
  for (int n=0;n<4;++n){
    int s = (int)n0 + wn + n*16;          // start col, multiple of 16
    float bs = bias[s + l15];
    int g = s >> 10, jgi = (s & 1023) >> 4;
    #pragma unroll
    for (int m=0;m<4;++m){
      #pragma unroll
      for (int rg=0; rg<4; ++rg){
        u32 w0 = (u32)(unsigned short)bf16b(acc[m][n][rg] + bs);
        u32 w1 = __shfl_down(w0, 1);
        u32 w2 = __shfl_down(w0, 2);
        u32 w3 = __shfl_down(w0, 3);
        if ((l15 & 3) == 0){
          u64 pk = (u64)w0 | ((u64)w1<<16) | ((u64)w2<<32) | ((u64)w3<<48);
          int rowin = wm + m*16 + quad*4 + rg;    // batch b 0..127
          *(u64*)(C + (((size_t)bm*64 + jgi)*128 + rowin)*64 + g*16 + l15) = pk;
        }
      }
    }
  }
}

// ---- phase 2: persistent LSTM recurrence ----
// 256 blocks x 512 threads. bg = blockIdx&3 (XCD-paired), jg = blockIdx>>2.
// h_all[t] = fresh buffer per step: producers sc1 write-through stores,
// consumers PLAIN CACHED loads (cold addresses -> coherent, no fences).
// Whh in LDS, fragment-major (conflict-free). One arrival counter per b-group.
__global__ __launch_bounds__(512,1) void lstm_kernel(
    const short* __restrict__ whh, const short* __restrict__ xw,
    short* __restrict__ h_all, u32* __restrict__ cnts)
{
  __shared__ __align__(16) short whh_s[65536];   // 128 KB fragment-major
  __shared__ f32x4 part[8][2][64];               // 16 KB

  const int tid  = threadIdx.x;
  const int lane = tid & 63;
  const int wave = tid >> 6;         // K-slice 0..7 (128 each)
  const int l15  = lane & 15;
  const int quad = lane >> 4;
  const int bg = blockIdx.x & 3;     // b-group: lands on XCDs {bg, bg+4}
  const int jg = blockIdx.x >> 2;    // 0..63
  const int b0 = bg*32;
  const int j0 = jg*16;
  const int ks0 = wave*128;

  __builtin_amdgcn_fence(__ATOMIC_ACQUIRE, "agent");  // once: clear stale L2

  // preload Whh slice -> LDS, fragment-major: frag c=(w*16+g*4+kit), lane, 8
  for (int idx = tid; idx < 8192; idx += 512){
    int lane_ = idx & 63;
    int c = idx >> 6;                 // 0..127
    int w = c >> 4, g = (c >> 2) & 3, kit = c & 3;
    *(short8*)(whh_s + (size_t)idx*8) =
      *(const short8*)(whh + (size_t)(g*1024 + j0 + (lane_ & 15))*HID
                           + w*128 + kit*32 + (lane_ >> 4)*8);
  }

  u32* cnt_g = cnts + bg*64;          // 256B-spaced counters

  // elementwise mapping: cell = tid (bl 0..31 x jj 0..15)
  const int bl = tid >> 4;
  const int jj = tid & 15;
  const int mt_e = bl >> 4, re = bl & 15;
  const int ln = (re>>2)*16 + jj, rg = re & 3;
  float cc = 0.0f;                    // cell state in register

  // prefetch xw for t=0
  short xwc[4];
  {
    const short* xb = xw + (((size_t)0*64 + jg)*128 + b0 + bl)*64 + jj;
    #pragma unroll
    for (int g=0; g<4; ++g) xwc[g] = xb[g*16];
  }
  __syncthreads();   // whh_s ready

  for (int t = 0; t < SQLEN; ++t){
    const short* hin  = h_all + (size_t)t*131072;
    short*       hout = h_all + (size_t)(t+1)*131072;

    // prefetch next step's xw early (latency hidden under h-load + MFMA)
    short xwn[4];
    if (t < SQLEN-1){
      const short* xb = xw + (((size_t)(t+1)*64 + jg)*128 + b0 + bl)*64 + jj;
      #pragma unroll
      for (int g=0; g<4; ++g) xwn[g] = xb[g*16];
    }

    // h fragments: plain cached coalesced 16B loads (L2-shared per XCD)
    short8 Af[2][4];
    #pragma unroll
    for (int kit=0; kit<4; ++kit){
      #pragma unroll
      for (int mt=0; mt<2; ++mt)
        Af[mt][kit] = *(const short8*)(hin + (size_t)(b0 + mt*16 + l15)*HID
                                       + ks0 + kit*32 + quad*8);
    }

    f32x4 acc[2][4];
    #pragma unroll
    for (int mt=0; mt<2; ++mt)
      #pragma unroll
      for (int g=0; g<4; ++g) acc[mt][g] = (f32x4)0.0f;

    #pragma unroll
    for (int kit=0; kit<4; ++kit){
      #pragma unroll
      for (int g=0; g<4; ++g){
        short8 bfr = *(const short8*)(whh_s + (size_t)(((wave*16 + g*4 + kit)*64 + lane))*8);
        acc[0][g] = __builtin_amdgcn_mfma_f32_16x16x32_bf16(Af[0][kit], bfr, acc[0][g],0,0,0);
        acc[1][g] = __builtin_amdgcn_mfma_f32_16x16x32_bf16(Af[1][kit], bfr, acc[1][g],0,0,0);
      }
    }

    // 4-stage cross-wave gate reduce
    float gv[4];
    #pragma unroll
    for (int g=0; g<4; ++g){
      part[wave][0][lane] = acc[0][g];
      part[wave][1][lane] = acc[1][g];
      __syncthreads();
      float s = bf2f(xwc[g]);
      #pragma unroll
      for (int w=0; w<8; ++w)
        s += ((const float*)&part[w][mt_e][ln])[rg];
      gv[g] = s;
      __syncthreads();
    }

    float it = sigm(gv[0]), ft = sigm(gv[1]), ch = tanhx(gv[2]), ot = sigm(gv[3]);
    cc = cc*ft + it*ch;
    float hv = ot * tanhx(cc);

    // pack 4 adjacent cells -> one 8B sc1 write-through store
    u32 w0 = (u32)(unsigned short)bf16b(hv);
    u32 w1 = __shfl_down(w0, 1);
    u32 w2 = __shfl_down(w0, 2);
    u32 w3 = __shfl_down(w0, 3);
    if (!(lane & 3)){
      u64 hp = (u64)w0 | ((u64)w1<<16) | ((u64)w2<<32) | ((u64)w3<<48);
      __hip_atomic_store((u64*)(hout + (size_t)(b0 + bl)*HID + j0 + jj), hp,
                         __ATOMIC_RELAXED, __HIP_MEMORY_SCOPE_AGENT);
    }
    xwc[0]=xwn[0]; xwc[1]=xwn[1]; xwc[2]=xwn[2]; xwc[3]=xwn[3];
    __syncthreads();   // h stores drained (vmcnt0 at barrier)

    if (t < SQLEN-1){
      if (tid == 0)
        (void)__hip_atomic_fetch_add(cnt_g, 1u, __ATOMIC_RELAXED,
                                     __HIP_MEMORY_SCOPE_AGENT);
      if (tid == 0){
        const u32 target = 64u*(u32)(t+1);
        while (__hip_atomic_load(cnt_g, __ATOMIC_RELAXED,
                                 __HIP_MEMORY_SCOPE_AGENT) < target)
          __builtin_amdgcn_s_sleep(1);
      }
      __syncthreads();
    }
  }
}

// ---- phase 3: out[b][c] = h[b]. Wfc[c] + bfc[c], fp32 ----
__global__ __launch_bounds__(256) void fc_kernel(const short* __restrict__ h,
    const float* __restrict__ wfc, const float* __restrict__ bfc, float* __restrict__ out)
{
  __shared__ float hs[4][1024];
  int tid = threadIdx.x;
  int b0 = blockIdx.x*4;
  for (int i = tid; i < 4096; i += 256){
    int bb = i >> 10, k = i & 1023;
    hs[bb][k] = bf2f(h[(size_t)(b0+bb)*HID + k]);
  }
  __syncthreads();
  for (int c = tid; c < NCLS; c += 256){
    const float* w = wfc + (size_t)c*HID;
    float a0=0.f,a1=0.f,a2=0.f,a3=0.f;
    for (int k=0; k<1024; k+=4){
      float4 wv = *(const float4*)(w + k);
      a0 += wv.x*hs[0][k] + wv.y*hs[0][k+1] + wv.z*hs[0][k+2] + wv.w*hs[0][k+3];
      a1 += wv.x*hs[1][k] + wv.y*hs[1][k+1] + wv.z*hs[1][k+2] + wv.w*hs[1][k+3];
      a2 += wv.x*hs[2][k] + wv.y*hs[2][k+1] + wv.z*hs[2][k+2] + wv.w*hs[2][k+3];
      a3 += wv.x*hs[3][k] + wv.y*hs[3][k+1] + wv.z*hs[3][k+2] + wv.w*hs[3][k+3];
    }
    float bb = bfc[c];
    out[(size_t)(b0+0)*NCLS + c] = a0 + bb;
    out[(size_t)(b0+1)*NCLS + c] = a1 + bb;
    out[(size_t)(b0+2)*NCLS + c] = a2 + bb;
    out[(size_t)(b0+3)*NCLS + c] = a3 + bb;
  }
}

extern "C" void kernel_launch(void* const* d_in, const int* in_sizes, int n_in,
                              void* d_out, int out_size, void* d_ws, size_t ws_size,
                              hipStream_t stream) {
  const float* x   = (const float*)d_in[0];
  const float* Wxh = (const float*)d_in[1];
  const float* bxh = (const float*)d_in[2];
  const float* Whh = (const float*)d_in[3];
  const float* bhh = (const float*)d_in[4];
  const float* Wfc = (const float*)d_in[5];
  const float* bfc = (const float*)d_in[6];
  float* out = (float*)d_out;

  char* ws = (char*)d_ws;
  // h_all (257 x 256KB = 64.25MB) ALIASES xbf (64MB): xbf dead after gemm.
  short*    h_all = (short*)(ws + 0);
  short*    xbf   = (short*)(ws + 0);
  short*    wxhb  = (short*)(ws + 68157440);     // 65 MB
  short*    whhb  = (short*)(ws + 76546048);     // 73 MB
  float*    biasg = (float*)(ws + 84934656);     // 81 MB
  short*    xw    = (short*)(ws + 85983232);     // 82 MB, 256 MB gate-blocked
  u32*      cnts  = (u32*)(ws + 354418688);      // 4 counters, 256B apart

  hipMemsetAsync(cnts, 0, 4096, stream);

  cast_x_kernel<<<32768, 256, 0, stream>>>(x, xbf);
  cast_w_kernel<<<4096, 256, 0, stream>>>(Wxh, wxhb);
  cast_w_kernel<<<4096, 256, 0, stream>>>(Whh, whhb);
  bias_kernel  <<<16,   256, 0, stream>>>(bxh, bhh, biasg);
  gemm_xw_kernel<<<8192, 256, 0, stream>>>(xbf, wxhb, biasg, xw);
  // xbf now dead; zero h_all[0] (t=0 input state)
  hipMemsetAsync(ws, 0, 262144, stream);
  lstm_kernel  <<<256,  512, 0, stream>>>(whhb, xw, h_all, cnts);
  fc_kernel    <<<32,   256, 0, stream>>>(h_all + (size_t)SQLEN*131072, Wfc, bfc, out);
}